// Round 1
// baseline (90.322 us; speedup 1.0000x reference)
//
#include <hip/hip_runtime.h>

#define QDIM 21
#define NDIM 1368
#define OUTSTRIDE 64000

typedef __attribute__((ext_vector_type(4))) float f32x4;
typedef __attribute__((ext_vector_type(8))) short bf16x8s;

static __device__ __forceinline__ unsigned short f2bf(float f) {
    unsigned int u = __float_as_uint(f);
    unsigned int r = (u + 0x7FFFu + ((u >> 16) & 1u)) >> 16;
    return (unsigned short)r;
}

// One block computes C[0:64, n0:n0+64] for window position p of one filterbank.
// C[b, dd] = sum_f win[b, f] * W[p*D+dd, f],  f = q*w + j, win value = x[b, q, start+j].
template<int WLOG2>
__global__ __launch_bounds__(256)
void fbk_kernel(const float* __restrict__ x, const float* __restrict__ W,
                float* __restrict__ out, int S, int D, int P, int K) {
    constexpr int WWIN = 1 << WLOG2;
    const int n0 = blockIdx.x * 64;
    const int p  = blockIdx.y;
    const int start = (p == P - 1) ? (NDIM - WWIN) : p * S;

    __shared__ unsigned short As[64][72];  // win tile, bf16, +8 pad
    __shared__ unsigned short Bs[64][72];  // W tile, bf16, +8 pad

    const int tid  = threadIdx.x;
    const int wid  = tid >> 6;
    const int lane = tid & 63;
    const int wm = (wid >> 1) * 32;   // wave's M offset (batch)
    const int wn = (wid & 1) * 32;    // wave's N offset (dd)
    const int lr = lane & 15;         // row-in-frag (A) / col-in-frag (B,C)
    const int kb = (lane >> 4) * 8;   // k sub-offset within 32

    const float* Wp = W + (size_t)(p * D + n0) * K;

    f32x4 acc[2][2] = {};

    const int ktiles = (K + 63) >> 6;
    for (int kt = 0; kt < ktiles; ++kt) {
        const int kbase = kt * 64;
        // ---- stage A (x windows) and B (weights), f32 -> bf16, into LDS ----
        #pragma unroll
        for (int i = 0; i < 4; ++i) {
            int idx = tid + i * 256;      // 0..1023
            int row = idx >> 4;           // 0..63
            int c4  = (idx & 15) * 4;     // 0..60, step 4
            int f = kbase + c4;
            float4 va = make_float4(0.f, 0.f, 0.f, 0.f);
            float4 vb = make_float4(0.f, 0.f, 0.f, 0.f);
            if (f < K) {
                int q = f >> WLOG2;
                int j = f & (WWIN - 1);
                va = *(const float4*)(x + ((size_t)row * QDIM + q) * NDIM + start + j);
                vb = *(const float4*)(Wp + (size_t)row * K + f);
            }
            ushort4 ua, ub;
            ua.x = f2bf(va.x); ua.y = f2bf(va.y); ua.z = f2bf(va.z); ua.w = f2bf(va.w);
            ub.x = f2bf(vb.x); ub.y = f2bf(vb.y); ub.z = f2bf(vb.z); ub.w = f2bf(vb.w);
            *(ushort4*)(&As[row][c4]) = ua;
            *(ushort4*)(&Bs[row][c4]) = ub;
        }
        __syncthreads();
        // ---- MFMA: 2 k-steps of 32, 2x2 fragments per wave ----
        #pragma unroll
        for (int kk = 0; kk < 2; ++kk) {
            int ko = kk * 32 + kb;
            bf16x8s a0 = *(const bf16x8s*)(&As[wm + lr][ko]);
            bf16x8s a1 = *(const bf16x8s*)(&As[wm + 16 + lr][ko]);
            bf16x8s b0 = *(const bf16x8s*)(&Bs[wn + lr][ko]);
            bf16x8s b1 = *(const bf16x8s*)(&Bs[wn + 16 + lr][ko]);
            acc[0][0] = __builtin_amdgcn_mfma_f32_16x16x32_bf16(a0, b0, acc[0][0], 0, 0, 0);
            acc[0][1] = __builtin_amdgcn_mfma_f32_16x16x32_bf16(a0, b1, acc[0][1], 0, 0, 0);
            acc[1][0] = __builtin_amdgcn_mfma_f32_16x16x32_bf16(a1, b0, acc[1][0], 0, 0, 0);
            acc[1][1] = __builtin_amdgcn_mfma_f32_16x16x32_bf16(a1, b1, acc[1][1], 0, 0, 0);
        }
        __syncthreads();
    }

    // ---- epilogue: C/D layout col = lane&15, row = (lane>>4)*4 + r ----
    const int colbase = p * D + n0;
    #pragma unroll
    for (int mi = 0; mi < 2; ++mi) {
        #pragma unroll
        for (int ni = 0; ni < 2; ++ni) {
            int col = colbase + wn + ni * 16 + lr;
            int rbase = wm + mi * 16 + (lane >> 4) * 4;
            #pragma unroll
            for (int r = 0; r < 4; ++r) {
                out[(size_t)(rbase + r) * OUTSTRIDE + col] = acc[mi][ni][r];
            }
        }
    }
}

extern "C" void kernel_launch(void* const* d_in, const int* in_sizes, int n_in,
                              void* d_out, int out_size, void* d_ws, size_t ws_size,
                              hipStream_t stream) {
    const float* x  = (const float*)d_in[0];
    const float* w0 = (const float*)d_in[1];
    const float* w1 = (const float*)d_in[2];
    const float* w2 = (const float*)d_in[3];
    float* out = (float*)d_out;

    // fb0: w=16, s=4,  d=64,  P=338, K=336,  out col offset 0
    fbk_kernel<4><<<dim3(1, 338), 256, 0, stream>>>(x, w0, out,         4,  64,  338, 336);
    // fb1: w=32, s=8,  d=128, P=167, K=672,  out col offset 338*64 = 21632
    fbk_kernel<5><<<dim3(2, 167), 256, 0, stream>>>(x, w1, out + 21632, 8,  128, 167, 672);
    // fb2: w=64, s=16, d=256, P=82,  K=1344, out col offset 21632+167*128 = 43008
    fbk_kernel<6><<<dim3(4, 82),  256, 0, stream>>>(x, w2, out + 43008, 16, 256, 82,  1344);
}

// Round 2
// 51.188 us; speedup vs baseline: 1.7645x; 1.7645x over previous
//
#include <hip/hip_runtime.h>

#define QDIM 21
#define NDIM 1368
#define OUTSTRIDE 64000

typedef __attribute__((ext_vector_type(4))) float f32x4;
typedef __attribute__((ext_vector_type(8))) short bf16x8s;

static __device__ __forceinline__ unsigned short f2bf(float f) {
    unsigned int u = __float_as_uint(f);
    return (unsigned short)((u + 0x7FFFu + ((u >> 16) & 1u)) >> 16);
}

// One block computes C[0:64, n0:n0+64] for window position p of one filterbank.
// C[b, dd] = sum_f win[b, f] * W[p*D+dd, f],  f = q*w + j, win value = x[b, q, start+j].
template<int WLOG2, int NTX, int D, int P, int S, int K>
__device__ __forceinline__ void fbk_body(const float* __restrict__ x,
                                         const float* __restrict__ W,
                                         float* __restrict__ out,
                                         int bid,
                                         unsigned short (*As)[72],
                                         unsigned short (*Bs)[72]) {
    constexpr int WWIN = 1 << WLOG2;
    constexpr int KTILES = (K + 63) / 64;

    const int n0 = (bid % NTX) * 64;
    const int p  = bid / NTX;
    const int start = (p == P - 1) ? (NDIM - WWIN) : p * S;

    const int tid  = threadIdx.x;
    const int wid  = tid >> 6;
    const int lane = tid & 63;
    const int wm = (wid >> 1) * 32;   // wave's M offset (batch)
    const int wn = (wid & 1) * 32;    // wave's N offset (dd)
    const int lr = lane & 15;
    const int kb = (lane >> 4) * 8;

    const float* Wp = W + (size_t)(p * D + n0) * K;

    f32x4 acc[2][2] = {};
    float4 va[4], vb[4];   // prefetch registers (T14 async-STAGE split)

    auto load_tile = [&](int kbase) {
        #pragma unroll
        for (int i = 0; i < 4; ++i) {
            int idx = tid + i * 256;      // 0..1023
            int row = idx >> 4;           // 0..63
            int c4  = (idx & 15) * 4;     // 0..60 step 4
            int f = kbase + c4;
            if ((K % 64 == 0) || f < K) { // constexpr-true for fb2 (dominant)
                int q = f >> WLOG2;
                int j = f & (WWIN - 1);
                va[i] = *(const float4*)(x + ((size_t)row * QDIM + q) * NDIM + start + j);
                vb[i] = *(const float4*)(Wp + (size_t)row * K + f);
            } else {
                va[i] = make_float4(0.f, 0.f, 0.f, 0.f);
                vb[i] = make_float4(0.f, 0.f, 0.f, 0.f);
            }
        }
    };
    auto store_tile = [&]() {
        #pragma unroll
        for (int i = 0; i < 4; ++i) {
            int idx = tid + i * 256;
            int row = idx >> 4;
            int c4  = (idx & 15) * 4;
            ushort4 ua, ub;
            ua.x = f2bf(va[i].x); ua.y = f2bf(va[i].y);
            ua.z = f2bf(va[i].z); ua.w = f2bf(va[i].w);
            ub.x = f2bf(vb[i].x); ub.y = f2bf(vb[i].y);
            ub.z = f2bf(vb[i].z); ub.w = f2bf(vb[i].w);
            *(ushort4*)(&As[row][c4]) = ua;
            *(ushort4*)(&Bs[row][c4]) = ub;
        }
    };

    load_tile(0);
    store_tile();
    __syncthreads();

    #pragma unroll 1
    for (int kt = 0; kt < KTILES; ++kt) {
        if (kt + 1 < KTILES) load_tile((kt + 1) * 64);   // issue next tile's VMEM early
        #pragma unroll
        for (int kk = 0; kk < 2; ++kk) {
            int ko = kk * 32 + kb;
            bf16x8s a0 = *(const bf16x8s*)(&As[wm + lr][ko]);
            bf16x8s a1 = *(const bf16x8s*)(&As[wm + 16 + lr][ko]);
            bf16x8s b0 = *(const bf16x8s*)(&Bs[wn + lr][ko]);
            bf16x8s b1 = *(const bf16x8s*)(&Bs[wn + 16 + lr][ko]);
            acc[0][0] = __builtin_amdgcn_mfma_f32_16x16x32_bf16(a0, b0, acc[0][0], 0, 0, 0);
            acc[0][1] = __builtin_amdgcn_mfma_f32_16x16x32_bf16(a0, b1, acc[0][1], 0, 0, 0);
            acc[1][0] = __builtin_amdgcn_mfma_f32_16x16x32_bf16(a1, b0, acc[1][0], 0, 0, 0);
            acc[1][1] = __builtin_amdgcn_mfma_f32_16x16x32_bf16(a1, b1, acc[1][1], 0, 0, 0);
        }
        __syncthreads();
        if (kt + 1 < KTILES) store_tile();               // waits vmcnt, writes LDS
        __syncthreads();
    }

    // epilogue: C/D layout col = lane&15, row = (lane>>4)*4 + r
    const int colbase = p * D + n0;
    #pragma unroll
    for (int mi = 0; mi < 2; ++mi) {
        #pragma unroll
        for (int ni = 0; ni < 2; ++ni) {
            int col = colbase + wn + ni * 16 + lr;
            int rbase = wm + mi * 16 + (lane >> 4) * 4;
            #pragma unroll
            for (int r = 0; r < 4; ++r) {
                out[(size_t)(rbase + r) * OUTSTRIDE + col] = acc[mi][ni][r];
            }
        }
    }
}

// Fused dispatch: 1000 blocks. Big fb2 blocks (21 K-tiles) first for tail packing,
// then fb1 (11), then fb0 (6).
__global__ __launch_bounds__(256)
void fbk_fused(const float* __restrict__ x,  const float* __restrict__ w0,
               const float* __restrict__ w1, const float* __restrict__ w2,
               float* __restrict__ out) {
    __shared__ unsigned short As[64][72];
    __shared__ unsigned short Bs[64][72];
    const int bid = blockIdx.x;
    if (bid < 328) {
        // fb2: w=64, s=16, d=256, P=82, K=1344, 4 n-tiles
        fbk_body<6, 4, 256, 82, 16, 1344>(x, w2, out + 43008, bid, As, Bs);
    } else if (bid < 662) {
        // fb1: w=32, s=8, d=128, P=167, K=672, 2 n-tiles
        fbk_body<5, 2, 128, 167, 8, 672>(x, w1, out + 21632, bid - 328, As, Bs);
    } else {
        // fb0: w=16, s=4, d=64, P=338, K=336, 1 n-tile
        fbk_body<4, 1, 64, 338, 4, 336>(x, w0, out, bid - 662, As, Bs);
    }
}

extern "C" void kernel_launch(void* const* d_in, const int* in_sizes, int n_in,
                              void* d_out, int out_size, void* d_ws, size_t ws_size,
                              hipStream_t stream) {
    const float* x  = (const float*)d_in[0];
    const float* w0 = (const float*)d_in[1];
    const float* w1 = (const float*)d_in[2];
    const float* w2 = (const float*)d_in[3];
    float* out = (float*)d_out;
    fbk_fused<<<dim3(1000), 256, 0, stream>>>(x, w0, w1, w2, out);
}